// Round 1
// baseline (212.052 us; speedup 1.0000x reference)
//
#include <hip/hip_runtime.h>

#define BATCH 1024
#define V 20
#define S 30
#define D 128
#define H0 256
#define H1 128
#define NCLASS 20
#define VS (V * S)   // 600

__global__ __launch_bounds__(256, 4) void fcnc_fused_kernel(
    const int* __restrict__ diag_idx,
    const int* __restrict__ proc_idx,
    const float* __restrict__ emb,
    const float* __restrict__ W0, const float* __restrict__ b0,
    const float* __restrict__ W1, const float* __restrict__ b1,
    const float* __restrict__ W2, const float* __restrict__ b2,
    float* __restrict__ out)
{
    __shared__ int sidx[2 * VS];                              // 4.8 KB
    __shared__ __attribute__((aligned(16))) float red[8][D];  // 4 KB
    __shared__ __attribute__((aligned(16))) float x[2 * D];   // 1 KB
    __shared__ __attribute__((aligned(16))) float h0[H0];     // 1 KB
    __shared__ __attribute__((aligned(16))) float h1[H1];     // 0.5 KB

    const int b = blockIdx.x;
    const int tid = threadIdx.x;

    // ---- Phase A: stage this sample's indices into LDS ----
    const int* dsrc = diag_idx + b * VS;
    const int* psrc = proc_idx + b * VS;
    for (int i = tid; i < VS; i += 256) {
        sidx[i] = dsrc[i];
        sidx[VS + i] = psrc[i];
    }
    __syncthreads();

    // ---- Phase B: gather-accumulate ----
    // 8 groups of 32 lanes. Groups 0-3: diag pool; groups 4-7: proc pool.
    // Each group covers rows r = g, g+4, ... (150 rows); lane l holds float4
    // at columns [4l, 4l+3] -> one row = 32 lanes x 16B = coalesced 512B.
    const int grp  = tid >> 5;
    const int lane = tid & 31;
    const int sub  = grp & 3;
    const int poolOff = (grp >> 2) * VS;
    float4 acc = make_float4(0.f, 0.f, 0.f, 0.f);
    #pragma unroll 4
    for (int r = sub; r < VS; r += 4) {
        const int row = sidx[poolOff + r];
        const float4 e = ((const float4*)(emb + (size_t)row * D))[lane];
        acc.x += e.x; acc.y += e.y; acc.z += e.z; acc.w += e.w;
    }
    ((float4*)red[grp])[lane] = acc;
    __syncthreads();

    // ---- Phase C: cross-group reduce -> x[256] = concat(diag, proc) / 30 ----
    {
        const int pool = tid >> 7;       // 0: diag, 1: proc
        const int d    = tid & 127;
        const float s = red[pool * 4 + 0][d] + red[pool * 4 + 1][d]
                      + red[pool * 4 + 2][d] + red[pool * 4 + 3][d];
        x[tid] = s * (1.0f / 30.0f);     // mean over S then sum over V
    }
    __syncthreads();

    // ---- Phase D: fc0 (256 -> 256), relu stored for next layer ----
    {
        const float4* wrow = (const float4*)(W0 + tid * (2 * D));
        const float4* xv   = (const float4*)x;
        float a0 = 0.f;
        #pragma unroll 8
        for (int k = 0; k < 64; ++k) {
            const float4 w = wrow[k];
            const float4 xx = xv[k];
            a0 += w.x * xx.x + w.y * xx.y + w.z * xx.z + w.w * xx.w;
        }
        a0 += b0[tid];
        h0[tid] = fmaxf(a0, 0.f);        // relu before fc1
    }
    __syncthreads();

    // ---- fc1 (256 -> 128) ----
    if (tid < H1) {
        const float4* wrow = (const float4*)(W1 + tid * H0);
        const float4* hv   = (const float4*)h0;
        float a1 = 0.f;
        #pragma unroll 8
        for (int k = 0; k < 64; ++k) {
            const float4 w = wrow[k];
            const float4 hh = hv[k];
            a1 += w.x * hh.x + w.y * hh.y + w.z * hh.z + w.w * hh.w;
        }
        a1 += b1[tid];
        h1[tid] = fmaxf(a1, 0.f);        // relu before fc2
    }
    __syncthreads();

    // ---- fc2 (128 -> 20), final (no relu) ----
    if (tid < NCLASS) {
        const float4* wrow = (const float4*)(W2 + tid * H1);
        const float4* hv   = (const float4*)h1;
        float a2 = 0.f;
        #pragma unroll
        for (int k = 0; k < 32; ++k) {
            const float4 w = wrow[k];
            const float4 hh = hv[k];
            a2 += w.x * hh.x + w.y * hh.y + w.z * hh.z + w.w * hh.w;
        }
        out[b * NCLASS + tid] = a2 + b2[tid];
    }
}

extern "C" void kernel_launch(void* const* d_in, const int* in_sizes, int n_in,
                              void* d_out, int out_size, void* d_ws, size_t ws_size,
                              hipStream_t stream) {
    const int*   diag_idx = (const int*)d_in[0];
    const int*   proc_idx = (const int*)d_in[1];
    const float* emb      = (const float*)d_in[2];
    const float* W0       = (const float*)d_in[3];
    const float* b0       = (const float*)d_in[4];
    const float* W1       = (const float*)d_in[5];
    const float* b1       = (const float*)d_in[6];
    const float* W2       = (const float*)d_in[7];
    const float* b2       = (const float*)d_in[8];
    float* out = (float*)d_out;

    fcnc_fused_kernel<<<BATCH, 256, 0, stream>>>(
        diag_idx, proc_idx, emb, W0, b0, W1, b1, W2, b2, out);
}